// Round 14
// baseline (398.158 us; speedup 1.0000x reference)
//
#include <hip/hip_runtime.h>
#include <hip/hip_bf16.h>
#include <stdint.h>

#define N_TOK 2048
#define HID   2048
#define NEXP  8
#define DFF   1408

typedef __attribute__((ext_vector_type(8))) short short8;
typedef __attribute__((ext_vector_type(4))) float f32x4;

__device__ __forceinline__ unsigned short f2bf(float f) {
  union { float ff; uint32_t u; } v; v.ff = f;
  return (unsigned short)((v.u + 0x7FFFu + ((v.u >> 16) & 1u)) >> 16);
}
__device__ __forceinline__ float bf2f(unsigned short u) {
  union { uint32_t i; float f; } v; v.i = (uint32_t)u << 16; return v.f;
}

__device__ __forceinline__ void gl2lds16(const void* g, void* l) {
  __builtin_amdgcn_global_load_lds(
      (const __attribute__((address_space(1))) void*)g,
      (__attribute__((address_space(3))) void*)l, 16, 0, 0);
}

#define MFMA16(a, b, c) __builtin_amdgcn_mfma_f32_16x16x32_bf16((a), (b), (c), 0, 0, 0)

// ---------------- K1: gating + fused h->bf16 conversion ----------------
__global__ __launch_bounds__(256) void gate_topk_k(
    const float* __restrict__ h, const float* __restrict__ gw,
    int* __restrict__ cnt, int* __restrict__ topk_idx, float* __restrict__ topk_w,
    unsigned short* __restrict__ hbf)
{
  int token = blockIdx.x * 4 + (threadIdx.x >> 6);
  int lane  = threadIdx.x & 63;
  const float* hr = h + (size_t)token * HID;
  float acc[NEXP];
#pragma unroll
  for (int e = 0; e < NEXP; ++e) acc[e] = 0.f;
  for (int c = lane * 8; c < HID; c += 512) {
    float4 a = *(const float4*)(hr + c);
    float4 b = *(const float4*)(hr + c + 4);
    unsigned short o[8] = {f2bf(a.x), f2bf(a.y), f2bf(a.z), f2bf(a.w),
                           f2bf(b.x), f2bf(b.y), f2bf(b.z), f2bf(b.w)};
    *(short8*)&hbf[(size_t)token * HID + c] = *(const short8*)o;
#pragma unroll
    for (int e = 0; e < NEXP; ++e) {
      const float* gp = gw + (size_t)e * HID + c;
      float4 ga = *(const float4*)gp;
      float4 gb = *(const float4*)(gp + 4);
      acc[e] = fmaf(a.x, ga.x, fmaf(a.y, ga.y, fmaf(a.z, ga.z, fmaf(a.w, ga.w,
               fmaf(b.x, gb.x, fmaf(b.y, gb.y, fmaf(b.z, gb.z, fmaf(b.w, gb.w, acc[e]))))))));
    }
  }
#pragma unroll
  for (int e = 0; e < NEXP; ++e) {
    float a = acc[e];
#pragma unroll
    for (int s = 32; s > 0; s >>= 1) a += __shfl_xor(a, s, 64);
    acc[e] = a;
  }
  if (lane == 0) {
    float m = acc[0];
#pragma unroll
    for (int e = 1; e < NEXP; ++e) m = fmaxf(m, acc[e]);
    float w[NEXP]; float s = 0.f;
#pragma unroll
    for (int e = 0; e < NEXP; ++e) { w[e] = __expf(acc[e] - m); s += w[e]; }
    float inv = 1.f / s;
    int i0 = 0; float b0 = acc[0];
#pragma unroll
    for (int e = 1; e < NEXP; ++e) if (acc[e] > b0) { b0 = acc[e]; i0 = e; }
    int i1 = -1; float b1 = -3.4e38f;
#pragma unroll
    for (int e = 0; e < NEXP; ++e) if (e != i0 && acc[e] > b1) { b1 = acc[e]; i1 = e; }
    topk_idx[token * 2 + 0] = i0;
    topk_idx[token * 2 + 1] = i1;
    topk_w[token * 2 + 0] = w[i0] * inv;
    topk_w[token * 2 + 1] = w[i1] * inv;
    atomicAdd(&cnt[i0], 1);
    atomicAdd(&cnt[i1], 1);
  }
}

// ---------------- K2: prefix ----------------
__global__ void prefix_k(const int* __restrict__ cnt, int* __restrict__ offs,
                         int* __restrict__ cursor) {
  if (threadIdx.x == 0 && blockIdx.x == 0) {
    int s = 0;
    for (int e = 0; e < NEXP; ++e) { offs[e] = s; cursor[e] = s; s += cnt[e]; }
  }
}

// ---------------- K3: scatter (+ inverse map tok_slot) ----------------
__global__ __launch_bounds__(256) void scatter_k(
    const int* __restrict__ topk_idx, const float* __restrict__ topk_w,
    int* __restrict__ cursor, int* __restrict__ pair_token, float* __restrict__ pair_w,
    int* __restrict__ tok_slot)
{
  int n = blockIdx.x * 256 + threadIdx.x;
  if (n >= N_TOK) return;
#pragma unroll
  for (int k = 0; k < 2; ++k) {
    int e = topk_idx[n * 2 + k];
    int p = atomicAdd(&cursor[e], 1);
    pair_token[p] = n;
    pair_w[p] = topk_w[n * 2 + k];
    tok_slot[n * 2 + k] = p;
  }
}

// ---------------- K5: transpose-convert fp32 [z][R][C] -> bf16 [z][C][R] ----------------
__global__ __launch_bounds__(256) void transpose_k(const float* __restrict__ s1,
                                                   unsigned short* __restrict__ d1,
                                                   const float* __restrict__ s2,
                                                   unsigned short* __restrict__ d2,
                                                   int R, int C, int nz1)
{
  __shared__ unsigned short T[64 * 66];
  const size_t sl = (size_t)R * C;
  int z = blockIdx.z;
  const float* s; unsigned short* d;
  if (z < nz1) { s = s1 + (size_t)z * sl; d = d1 + (size_t)z * sl; }
  else { s = s2 + (size_t)(z - nz1) * sl; d = d2 + (size_t)(z - nz1) * sl; }
  const int rb = blockIdx.x * 64, cb = blockIdx.y * 64;
  const int t = threadIdx.x;
  const int tr = t >> 4, tc = (t & 15) * 4;
  const float* sp = s + (size_t)(rb + tr) * C + cb + tc;
#pragma unroll
  for (int i = 0; i < 4; ++i) {
    float4 v = *(const float4*)(sp + (size_t)i * 16 * C);
    int r = tr + i * 16;
    uint32_t p0 = (uint32_t)f2bf(v.x) | ((uint32_t)f2bf(v.y) << 16);
    uint32_t p1 = (uint32_t)f2bf(v.z) | ((uint32_t)f2bf(v.w) << 16);
    *(uint32_t*)&T[r * 66 + tc]     = p0;
    *(uint32_t*)&T[r * 66 + tc + 2] = p1;
  }
  __syncthreads();
  const int f = t >> 2, ch = (t & 3) * 16;
  unsigned short* dp = d + (size_t)(cb + f) * R + rb + ch;
#pragma unroll
  for (int g = 0; g < 2; ++g) {
    unsigned short buf[8];
#pragma unroll
    for (int j = 0; j < 8; ++j) buf[j] = T[(ch + g * 8 + j) * 66 + f];
    *(short8*)(dp + g * 8) = *(const short8*)buf;
  }
}

// ---------------- K6: grouped GEMM gate+up — weight-once (M512 x F64, 8 waves) ----
// Each block stages its 64-f weight panel exactly once (M-chunk covers the whole
// typical expert). BK=32, 64B LDS rows, swizzle chunk = fq ^ ((row>>1)&3) (2-way,
// free). dbuf + counted vmcnt(5) (5 gl2lds/wave/step). Grid 176 x 4 tile-queue.
__global__ __launch_bounds__(512) void gateup14_k(
    const unsigned short* __restrict__ hbf,
    const unsigned short* __restrict__ wgt, const unsigned short* __restrict__ wut,
    const int* __restrict__ cnt, const int* __restrict__ offs,
    const int* __restrict__ pair_token, unsigned short* __restrict__ act,
    int e_fixed, int nw, int nbcnt, size_t wstride)
{
  const int x = blockIdx.x;
  const int wti = x % nw, mc = x / nw;
  int e, nb;
  if (e_fixed >= 0) { e = e_fixed; nb = wti; }
  else { e = wti / nbcnt; nb = wti % nbcnt; }
  const int count = cnt[e];
  if (mc * 512 >= count) return;
  const int off = offs[e];
  const int m0 = mc * 512;
  const int rows = min(512, count - m0);
  const int c0 = nb * 64;

  __shared__ unsigned short As[2][512 * 32];
  __shared__ unsigned short Bg[2][64 * 32];
  __shared__ unsigned short Bu[2][64 * 32];
  __shared__ int tok[512];

  const int t = threadIdx.x;
  tok[t] = pair_token[off + m0 + min(t, rows - 1)];
  __syncthreads();

  const int w = t >> 6, l = t & 63;
  const int lr = l >> 2, lp = l & 3;
  const int swz = (lp ^ ((lr >> 1) & 3)) * 8;   // source chunk for linear LDS slot

  const size_t wb = (e_fixed >= 0) ? 0 : (size_t)e * wstride;
  const unsigned short* aP[4];
#pragma unroll
  for (int i = 0; i < 4; ++i)
    aP[i] = hbf + (size_t)tok[w * 64 + i * 16 + lr] * HID + swz;
  const unsigned short* bsrc = (w < 4)
      ? wgt + wb + (size_t)(c0 + w * 16 + lr) * HID + swz
      : wut + wb + (size_t)(c0 + (w - 4) * 16 + lr) * HID + swz;
  const int ldsA = (w * 64) * 32;
  const int ldsB = ((w & 3) * 16) * 32;

  const int fr = l & 15, fq = l >> 4;
  const int rch = (fq ^ ((fr >> 1) & 3)) * 8;   // read chunk offset (elements)

  f32x4 accg[4][4], accu[4][4];
#pragma unroll
  for (int i = 0; i < 4; ++i)
#pragma unroll
    for (int j = 0; j < 4; ++j) {
      accg[i][j] = (f32x4){0.f, 0.f, 0.f, 0.f};
      accu[i][j] = (f32x4){0.f, 0.f, 0.f, 0.f};
    }

  auto stage = [&](int b, int kt) {
#pragma unroll
    for (int i = 0; i < 4; ++i)
      gl2lds16(aP[i] + kt, &As[b][ldsA + i * 16 * 32]);
    if (w < 4) gl2lds16(bsrc + kt, &Bg[b][ldsB]);
    else       gl2lds16(bsrc + kt, &Bu[b][ldsB]);
  };
  auto compute = [&](int b) {
    short8 af[4], bg[4], bu[4];
#pragma unroll
    for (int mi = 0; mi < 4; ++mi)
      af[mi] = *(const short8*)&As[b][(w * 64 + mi * 16 + fr) * 32 + rch];
#pragma unroll
    for (int ni = 0; ni < 4; ++ni) {
      bg[ni] = *(const short8*)&Bg[b][(ni * 16 + fr) * 32 + rch];
      bu[ni] = *(const short8*)&Bu[b][(ni * 16 + fr) * 32 + rch];
    }
    __builtin_amdgcn_s_setprio(1);
#pragma unroll
    for (int mi = 0; mi < 4; ++mi)
#pragma unroll
      for (int ni = 0; ni < 4; ++ni) {
        accg[mi][ni] = MFMA16(af[mi], bg[ni], accg[mi][ni]);
        accu[mi][ni] = MFMA16(af[mi], bu[ni], accu[mi][ni]);
      }
    __builtin_amdgcn_s_setprio(0);
  };

  const int NK = HID / 32;     // 64
  stage(0, 0);
  int cur = 0;
  for (int k = 0; k + 1 < NK; ++k) {
    stage(cur ^ 1, (k + 1) * 32);
    asm volatile("s_waitcnt vmcnt(5)" ::: "memory");   // prev tile's 5 loads done
    asm volatile("s_barrier" ::: "memory");
    compute(cur);
    asm volatile("s_barrier" ::: "memory");            // WAR before overwrite
    cur ^= 1;
  }
  asm volatile("s_waitcnt vmcnt(0)" ::: "memory");
  asm volatile("s_barrier" ::: "memory");
  compute(cur);

#pragma unroll
  for (int mi = 0; mi < 4; ++mi)
#pragma unroll
    for (int ni = 0; ni < 4; ++ni)
#pragma unroll
      for (int j = 0; j < 4; ++j) {
        int r = w * 64 + mi * 16 + fq * 4 + j;
        if (r < rows) {
          float g = accg[mi][ni][j], u = accu[mi][ni][j];
          float a = (g / (1.f + __expf(-g))) * u;
          act[(size_t)(off + m0 + r) * DFF + (c0 + ni * 16 + fr)] = f2bf(a);
        }
      }
}

// ---------------- K7: grouped GEMM down — weight-once (M512 x C64, 4 waves) -------
__global__ __launch_bounds__(256) void down14_k(
    const unsigned short* __restrict__ act, const unsigned short* __restrict__ wdt,
    const int* __restrict__ cnt, const int* __restrict__ offs,
    unsigned short* __restrict__ ypair, int e_fixed, int nw, int nbcnt, size_t wstride)
{
  const int x = blockIdx.x;
  const int wti = x % nw, mc = x / nw;
  int e, nc;
  if (e_fixed >= 0) { e = e_fixed; nc = wti; }
  else { e = wti / nbcnt; nc = wti % nbcnt; }
  const int count = cnt[e];
  if (mc * 512 >= count) return;
  const int off = offs[e];
  const int m0 = mc * 512;
  const int rows = min(512, count - m0);
  const int c0 = nc * 64;

  __shared__ unsigned short As[2][512 * 32];
  __shared__ unsigned short Bd[2][64 * 32];

  const int t = threadIdx.x;
  const int w = t >> 6, l = t & 63;
  const int lr = l >> 2, lp = l & 3;
  const int swz = (lp ^ ((lr >> 1) & 3)) * 8;

  const size_t wb = (e_fixed >= 0) ? 0 : (size_t)e * wstride;
  const unsigned short* aP[8];
#pragma unroll
  for (int i = 0; i < 8; ++i) {
    int r = min(w * 128 + i * 16 + lr, rows - 1);
    aP[i] = act + (size_t)(off + m0 + r) * DFF + swz;
  }
  const unsigned short* bsrc = wdt + wb + (size_t)(c0 + w * 16 + lr) * DFF + swz;
  const int ldsA = (w * 128) * 32;
  const int ldsB = (w * 16) * 32;

  const int fr = l & 15, fq = l >> 4;
  const int rch = (fq ^ ((fr >> 1) & 3)) * 8;

  f32x4 acc[8][4];
#pragma unroll
  for (int i = 0; i < 8; ++i)
#pragma unroll
    for (int j = 0; j < 4; ++j) acc[i][j] = (f32x4){0.f, 0.f, 0.f, 0.f};

  auto stage = [&](int b, int kt) {
#pragma unroll
    for (int i = 0; i < 8; ++i)
      gl2lds16(aP[i] + kt, &As[b][ldsA + i * 16 * 32]);
    gl2lds16(bsrc + kt, &Bd[b][ldsB]);
  };
  auto compute = [&](int b) {
    short8 af[8], bd[4];
#pragma unroll
    for (int mi = 0; mi < 8; ++mi)
      af[mi] = *(const short8*)&As[b][(w * 128 + mi * 16 + fr) * 32 + rch];
#pragma unroll
    for (int ni = 0; ni < 4; ++ni)
      bd[ni] = *(const short8*)&Bd[b][(ni * 16 + fr) * 32 + rch];
    __builtin_amdgcn_s_setprio(1);
#pragma unroll
    for (int mi = 0; mi < 8; ++mi)
#pragma unroll
      for (int ni = 0; ni < 4; ++ni)
        acc[mi][ni] = MFMA16(af[mi], bd[ni], acc[mi][ni]);
    __builtin_amdgcn_s_setprio(0);
  };

  const int NK = DFF / 32;     // 44
  stage(0, 0);
  int cur = 0;
  for (int k = 0; k + 1 < NK; ++k) {
    stage(cur ^ 1, (k + 1) * 32);
    asm volatile("s_waitcnt vmcnt(9)" ::: "memory");
    asm volatile("s_barrier" ::: "memory");
    compute(cur);
    asm volatile("s_barrier" ::: "memory");
    cur ^= 1;
  }
  asm volatile("s_waitcnt vmcnt(0)" ::: "memory");
  asm volatile("s_barrier" ::: "memory");
  compute(cur);

#pragma unroll
  for (int mi = 0; mi < 8; ++mi)
#pragma unroll
    for (int ni = 0; ni < 4; ++ni)
#pragma unroll
      for (int j = 0; j < 4; ++j) {
        int r = w * 128 + mi * 16 + fq * 4 + j;
        if (r < rows)
          ypair[(size_t)(off + m0 + r) * HID + (c0 + ni * 16 + fr)] = f2bf(acc[mi][ni][j]);
      }
}

// ---------------- K8: weighted combine (bf16 ypair) ----------------
__global__ __launch_bounds__(256) void combine_k(
    const unsigned short* __restrict__ ypair, const int* __restrict__ tok_slot,
    const float* __restrict__ topk_w, float* __restrict__ out)
{
  int i = blockIdx.x * 256 + threadIdx.x;       // over N_TOK * HID/8
  int n = i >> 8;
  int dv = (i & 255) * 8;
  int s0 = tok_slot[n * 2], s1 = tok_slot[n * 2 + 1];
  float w0 = topk_w[n * 2], w1 = topk_w[n * 2 + 1];
  short8 a = *(const short8*)&ypair[(size_t)s0 * HID + dv];
  short8 b = *(const short8*)&ypair[(size_t)s1 * HID + dv];
  float o[8];
#pragma unroll
  for (int j = 0; j < 8; ++j)
    o[j] = w0 * bf2f((unsigned short)a[j]) + w1 * bf2f((unsigned short)b[j]);
  *(float4*)&out[(size_t)n * HID + dv]     = *(const float4*)&o[0];
  *(float4*)&out[(size_t)n * HID + dv + 4] = *(const float4*)&o[4];
}

extern "C" void kernel_launch(void* const* d_in, const int* in_sizes, int n_in,
                              void* d_out, int out_size, void* d_ws, size_t ws_size,
                              hipStream_t stream) {
  const float* h  = (const float*)d_in[0];
  const float* gw = (const float*)d_in[1];
  const float* wg = (const float*)d_in[2];
  const float* wu = (const float*)d_in[3];
  const float* wd = (const float*)d_in[4];
  float* out = (float*)d_out;

  const size_t SL = (size_t)DFF * HID;
  char* ws = (char*)d_ws;
  int*   cnt        = (int*)(ws + 0);
  int*   offs       = (int*)(ws + 32);
  int*   cursor     = (int*)(ws + 64);
  int*   pair_token = (int*)(ws + 256);
  float* pair_w     = (float*)(ws + 16640);
  int*   tok_slot   = (int*)(ws + 33024);
  int*   topk_idx   = (int*)(ws + 49408);
  float* topk_w     = (float*)(ws + 65792);
  unsigned short* act = (unsigned short*)(ws + 82176);                // 11,534,336
  unsigned short* hbf = (unsigned short*)(ws + 11616512);             //  8,388,608
  unsigned short* wgt = (unsigned short*)(ws + 20005120);             // 46,137,344 (also wd^T)
  unsigned short* wut = (unsigned short*)(ws + 66142464);             // 46,137,344
  unsigned short* ypair_full = (unsigned short*)(ws + 66142464);      // aliases wut (down phase)
  const size_t NEED_FULL = 112279808ull;

  hipMemsetAsync(ws, 0, 256, stream);

  gate_topk_k<<<N_TOK / 4, 256, 0, stream>>>(h, gw, cnt, topk_idx, topk_w, hbf);
  prefix_k<<<1, 64, 0, stream>>>(cnt, offs, cursor);
  scatter_k<<<N_TOK / 256, 256, 0, stream>>>(topk_idx, topk_w, cursor, pair_token, pair_w, tok_slot);

  if (ws_size >= NEED_FULL) {
    transpose_k<<<dim3(HID / 64, DFF / 64, 16), 256, 0, stream>>>(wg, wgt, wu, wut, HID, DFF, 8);
    gateup14_k<<<176 * 4, 512, 0, stream>>>(hbf, wgt, wut, cnt, offs, pair_token, act,
                                            -1, 176, 22, SL);
    transpose_k<<<dim3(DFF / 64, HID / 64, 8), 256, 0, stream>>>(wd, wgt, wd, wgt, DFF, HID, 8);
    down14_k<<<256 * 4, 256, 0, stream>>>(act, wgt, cnt, offs, ypair_full,
                                          -1, 256, 32, SL);
    combine_k<<<(N_TOK * HID / 8) / 256, 256, 0, stream>>>(ypair_full, tok_slot, topk_w, out);
  } else {
    unsigned short* wgtE = (unsigned short*)(ws + 20005120);
    unsigned short* wutE = (unsigned short*)(ws + 25772288);
    unsigned short* ypair = (unsigned short*)(ws + 31539456);
    for (int e = 0; e < NEXP; ++e) {
      transpose_k<<<dim3(HID / 64, DFF / 64, 2), 256, 0, stream>>>(wg + e * SL, wgtE, wu + e * SL, wutE, HID, DFF, 1);
      gateup14_k<<<22 * 4, 512, 0, stream>>>(hbf, wgtE, wutE, cnt, offs, pair_token, act,
                                             e, 22, 22, 0);
    }
    for (int e = 0; e < NEXP; ++e) {
      transpose_k<<<dim3(DFF / 64, HID / 64, 1), 256, 0, stream>>>(wd + e * SL, wgtE, wd + e * SL, wgtE, DFF, HID, 1);
      down14_k<<<32 * 4, 256, 0, stream>>>(act, wgtE, cnt, offs, ypair, e, 32, 32, 0);
    }
    combine_k<<<(N_TOK * HID / 8) / 256, 256, 0, stream>>>(ypair, tok_slot, topk_w, out);
  }
}

// Round 15
// 340.758 us; speedup vs baseline: 1.1684x; 1.1684x over previous
//
#include <hip/hip_runtime.h>
#include <hip/hip_bf16.h>
#include <stdint.h>

#define N_TOK 2048
#define HID   2048
#define NEXP  8
#define DFF   1408

typedef __attribute__((ext_vector_type(8))) short short8;
typedef __attribute__((ext_vector_type(4))) float f32x4;

__device__ __forceinline__ unsigned short f2bf(float f) {
  union { float ff; uint32_t u; } v; v.ff = f;
  return (unsigned short)((v.u + 0x7FFFu + ((v.u >> 16) & 1u)) >> 16);
}

__device__ __forceinline__ void gl2lds16(const void* g, void* l) {
  __builtin_amdgcn_global_load_lds(
      (const __attribute__((address_space(1))) void*)g,
      (__attribute__((address_space(3))) void*)l, 16, 0, 0);
}

#define MFMA16(a, b, c) __builtin_amdgcn_mfma_f32_16x16x32_bf16((a), (b), (c), 0, 0, 0)

// ---------------- K1: gating + fused h->bf16 conversion ----------------
__global__ __launch_bounds__(256) void gate_topk_k(
    const float* __restrict__ h, const float* __restrict__ gw,
    int* __restrict__ cnt, int* __restrict__ topk_idx, float* __restrict__ topk_w,
    unsigned short* __restrict__ hbf)
{
  int token = blockIdx.x * 4 + (threadIdx.x >> 6);
  int lane  = threadIdx.x & 63;
  const float* hr = h + (size_t)token * HID;
  float acc[NEXP];
#pragma unroll
  for (int e = 0; e < NEXP; ++e) acc[e] = 0.f;
  for (int c = lane * 8; c < HID; c += 512) {
    float4 a = *(const float4*)(hr + c);
    float4 b = *(const float4*)(hr + c + 4);
    unsigned short o[8] = {f2bf(a.x), f2bf(a.y), f2bf(a.z), f2bf(a.w),
                           f2bf(b.x), f2bf(b.y), f2bf(b.z), f2bf(b.w)};
    *(short8*)&hbf[(size_t)token * HID + c] = *(const short8*)o;
#pragma unroll
    for (int e = 0; e < NEXP; ++e) {
      const float* gp = gw + (size_t)e * HID + c;
      float4 ga = *(const float4*)gp;
      float4 gb = *(const float4*)(gp + 4);
      acc[e] = fmaf(a.x, ga.x, fmaf(a.y, ga.y, fmaf(a.z, ga.z, fmaf(a.w, ga.w,
               fmaf(b.x, gb.x, fmaf(b.y, gb.y, fmaf(b.z, gb.z, fmaf(b.w, gb.w, acc[e]))))))));
    }
  }
#pragma unroll
  for (int e = 0; e < NEXP; ++e) {
    float a = acc[e];
#pragma unroll
    for (int s = 32; s > 0; s >>= 1) a += __shfl_xor(a, s, 64);
    acc[e] = a;
  }
  if (lane == 0) {
    float m = acc[0];
#pragma unroll
    for (int e = 1; e < NEXP; ++e) m = fmaxf(m, acc[e]);
    float w[NEXP]; float s = 0.f;
#pragma unroll
    for (int e = 0; e < NEXP; ++e) { w[e] = __expf(acc[e] - m); s += w[e]; }
    float inv = 1.f / s;
    int i0 = 0; float b0 = acc[0];
#pragma unroll
    for (int e = 1; e < NEXP; ++e) if (acc[e] > b0) { b0 = acc[e]; i0 = e; }
    int i1 = -1; float b1 = -3.4e38f;
#pragma unroll
    for (int e = 0; e < NEXP; ++e) if (e != i0 && acc[e] > b1) { b1 = acc[e]; i1 = e; }
    topk_idx[token * 2 + 0] = i0;
    topk_idx[token * 2 + 1] = i1;
    topk_w[token * 2 + 0] = w[i0] * inv;
    topk_w[token * 2 + 1] = w[i1] * inv;
    atomicAdd(&cnt[i0], 1);
    atomicAdd(&cnt[i1], 1);
  }
}

// ---------------- K2: prefix ----------------
__global__ void prefix_k(const int* __restrict__ cnt, int* __restrict__ offs,
                         int* __restrict__ cursor) {
  if (threadIdx.x == 0 && blockIdx.x == 0) {
    int s = 0;
    for (int e = 0; e < NEXP; ++e) { offs[e] = s; cursor[e] = s; s += cnt[e]; }
  }
}

// ---------------- K3: scatter ----------------
__global__ __launch_bounds__(256) void scatter_k(
    const int* __restrict__ topk_idx, const float* __restrict__ topk_w,
    int* __restrict__ cursor, int* __restrict__ pair_token, float* __restrict__ pair_w)
{
  int n = blockIdx.x * 256 + threadIdx.x;
  if (n >= N_TOK) return;
#pragma unroll
  for (int k = 0; k < 2; ++k) {
    int e = topk_idx[n * 2 + k];
    int p = atomicAdd(&cursor[e], 1);
    pair_token[p] = n;
    pair_w[p] = topk_w[n * 2 + k];
  }
}

// ---------------- K5: transpose-convert fp32 [z][R][C] -> bf16 [z][C][R] ----------------
__global__ __launch_bounds__(256) void transpose_k(const float* __restrict__ s1,
                                                   unsigned short* __restrict__ d1,
                                                   const float* __restrict__ s2,
                                                   unsigned short* __restrict__ d2,
                                                   int R, int C, int nz1)
{
  __shared__ unsigned short T[64 * 66];
  const size_t sl = (size_t)R * C;
  int z = blockIdx.z;
  const float* s; unsigned short* d;
  if (z < nz1) { s = s1 + (size_t)z * sl; d = d1 + (size_t)z * sl; }
  else { s = s2 + (size_t)(z - nz1) * sl; d = d2 + (size_t)(z - nz1) * sl; }
  const int rb = blockIdx.x * 64, cb = blockIdx.y * 64;
  const int t = threadIdx.x;
  const int tr = t >> 4, tc = (t & 15) * 4;
  const float* sp = s + (size_t)(rb + tr) * C + cb + tc;
#pragma unroll
  for (int i = 0; i < 4; ++i) {
    float4 v = *(const float4*)(sp + (size_t)i * 16 * C);
    int r = tr + i * 16;
    uint32_t p0 = (uint32_t)f2bf(v.x) | ((uint32_t)f2bf(v.y) << 16);
    uint32_t p1 = (uint32_t)f2bf(v.z) | ((uint32_t)f2bf(v.w) << 16);
    *(uint32_t*)&T[r * 66 + tc]     = p0;
    *(uint32_t*)&T[r * 66 + tc + 2] = p1;
  }
  __syncthreads();
  const int f = t >> 2, ch = (t & 3) * 16;
  unsigned short* dp = d + (size_t)(cb + f) * R + rb + ch;
#pragma unroll
  for (int g = 0; g < 2; ++g) {
    unsigned short buf[8];
#pragma unroll
    for (int j = 0; j < 8; ++j) buf[j] = T[(ch + g * 8 + j) * 66 + f];
    *(short8*)(dp + g * 8) = *(const short8*)buf;
  }
}

// ---------------- K6: grouped GEMM gate+up (64r x 64f dual, 4 waves, 48KB) --------
// R9 champion structure: dbuf + counted vmcnt(6), two barriers, tile queue.
__global__ __launch_bounds__(256) void gateup9_k(
    const unsigned short* __restrict__ hbf,
    const unsigned short* __restrict__ wgt, const unsigned short* __restrict__ wut,
    const int* __restrict__ cnt, const int* __restrict__ offs,
    const int* __restrict__ pair_token, unsigned short* __restrict__ act,
    int e_fixed, int nw, int nbcnt, size_t wstride)
{
  const int x = blockIdx.x;
  const int wti = x % nw, mb = x / nw;
  int e, nb;
  if (e_fixed >= 0) { e = e_fixed; nb = wti; }
  else { e = wti / nbcnt; nb = wti % nbcnt; }
  const int count = cnt[e];
  if (mb * 64 >= count) return;
  const int off = offs[e];
  const int rows = min(64, count - mb * 64);
  const int c0 = nb * 64;

  __shared__ unsigned short As[2][64 * 64];
  __shared__ unsigned short Bg[2][64 * 64];
  __shared__ unsigned short Bu[2][64 * 64];
  __shared__ int tok[64];

  const int t = threadIdx.x;
  if (t < 64) tok[t] = pair_token[off + mb * 64 + min(t, rows - 1)];
  __syncthreads();

  const int w = t >> 6, l = t & 63;
  const int sr = l >> 3;
  const int sc = ((l & 7) ^ sr) * 8;
  const int r0 = w * 16 + sr, r1 = w * 16 + 8 + sr;

  const size_t wb = (e_fixed >= 0) ? 0 : (size_t)e * wstride;
  const unsigned short* wgE = wgt + wb;
  const unsigned short* wuE = wut + wb;
  const unsigned short* aP0 = hbf + (size_t)tok[r0] * HID + sc;
  const unsigned short* aP1 = hbf + (size_t)tok[r1] * HID + sc;
  const unsigned short* gP0 = wgE + (size_t)(c0 + r0) * HID + sc;
  const unsigned short* gP1 = wgE + (size_t)(c0 + r1) * HID + sc;
  const unsigned short* uP0 = wuE + (size_t)(c0 + r0) * HID + sc;
  const unsigned short* uP1 = wuE + (size_t)(c0 + r1) * HID + sc;
  const int ldsLo = (w * 16) * 64, ldsHi = (w * 16 + 8) * 64;

  const int fr = l & 15, fq = l >> 4;
  const int wr = (w >> 1) * 32, wc = (w & 1) * 32;
  const int f3 = fr & 7;

  f32x4 accg[2][2], accu[2][2];
#pragma unroll
  for (int i = 0; i < 2; ++i)
#pragma unroll
    for (int j = 0; j < 2; ++j) {
      accg[i][j] = (f32x4){0.f, 0.f, 0.f, 0.f};
      accu[i][j] = (f32x4){0.f, 0.f, 0.f, 0.f};
    }

  auto stage = [&](int b, int kt) {
    gl2lds16(aP0 + kt, &As[b][ldsLo]); gl2lds16(aP1 + kt, &As[b][ldsHi]);
    gl2lds16(gP0 + kt, &Bg[b][ldsLo]); gl2lds16(gP1 + kt, &Bg[b][ldsHi]);
    gl2lds16(uP0 + kt, &Bu[b][ldsLo]); gl2lds16(uP1 + kt, &Bu[b][ldsHi]);
  };
  auto compute = [&](int b) {
    short8 af[2][2], bg[2][2], bu[2][2];
#pragma unroll
    for (int kk = 0; kk < 2; ++kk) {
      const int ch = ((kk * 4 + fq) ^ f3) * 8;
#pragma unroll
      for (int mi = 0; mi < 2; ++mi)
        af[mi][kk] = *(const short8*)&As[b][(wr + mi * 16 + fr) * 64 + ch];
#pragma unroll
      for (int ni = 0; ni < 2; ++ni) {
        bg[ni][kk] = *(const short8*)&Bg[b][(wc + ni * 16 + fr) * 64 + ch];
        bu[ni][kk] = *(const short8*)&Bu[b][(wc + ni * 16 + fr) * 64 + ch];
      }
    }
    __builtin_amdgcn_s_setprio(1);
#pragma unroll
    for (int kk = 0; kk < 2; ++kk)
#pragma unroll
      for (int mi = 0; mi < 2; ++mi)
#pragma unroll
        for (int ni = 0; ni < 2; ++ni) {
          accg[mi][ni] = MFMA16(af[mi][kk], bg[ni][kk], accg[mi][ni]);
          accu[mi][ni] = MFMA16(af[mi][kk], bu[ni][kk], accu[mi][ni]);
        }
    __builtin_amdgcn_s_setprio(0);
  };

  const int NK = HID / 64;     // 32
  stage(0, 0);
  int cur = 0;
  for (int k = 0; k + 1 < NK; ++k) {
    stage(cur ^ 1, (k + 1) * 64);
    asm volatile("s_waitcnt vmcnt(6)" ::: "memory");
    asm volatile("s_barrier" ::: "memory");
    compute(cur);
    asm volatile("s_barrier" ::: "memory");
    cur ^= 1;
  }
  asm volatile("s_waitcnt vmcnt(0)" ::: "memory");
  asm volatile("s_barrier" ::: "memory");
  compute(cur);

#pragma unroll
  for (int mi = 0; mi < 2; ++mi)
#pragma unroll
    for (int ni = 0; ni < 2; ++ni)
#pragma unroll
      for (int j = 0; j < 4; ++j) {
        int r = wr + mi * 16 + fq * 4 + j;
        if (r < rows) {
          float g = accg[mi][ni][j], u = accu[mi][ni][j];
          float a = (g / (1.f + __expf(-g))) * u;
          act[(size_t)(off + mb * 64 + r) * DFF + (c0 + wc + ni * 16 + fr)] = f2bf(a);
        }
      }
}

// ---------------- K7: grouped GEMM down (64 x 128, 4 waves, 48KB) -> atomic out ---
// R9 champion structure; epilogue scatters w*acc directly into out (2 commutative
// fp32 adds per element), removing ypair + combine traffic.
__global__ __launch_bounds__(256) void down9_k(
    const unsigned short* __restrict__ act, const unsigned short* __restrict__ wdt,
    const int* __restrict__ cnt, const int* __restrict__ offs,
    const int* __restrict__ pair_token, const float* __restrict__ pair_w,
    float* __restrict__ out, int e_fixed, int nw, int nbcnt, size_t wstride)
{
  const int x = blockIdx.x;
  const int wti = x % nw, mb = x / nw;
  int e, nb;
  if (e_fixed >= 0) { e = e_fixed; nb = wti; }
  else { e = wti / nbcnt; nb = wti % nbcnt; }
  const int count = cnt[e];
  if (mb * 64 >= count) return;
  const int off = offs[e];
  const int rows = min(64, count - mb * 64);
  const int c0 = nb * 128;

  __shared__ unsigned short As[2][64 * 64];
  __shared__ unsigned short Bd[2][128 * 64];

  const int t = threadIdx.x;
  const int w = t >> 6, l = t & 63;
  const int sr = l >> 3;
  const int sc = ((l & 7) ^ sr) * 8;
  const size_t wb = (e_fixed >= 0) ? 0 : (size_t)e * wstride;
  const unsigned short* wdE = wdt + wb;

  const int ra0 = min(w * 16 + sr, rows - 1), ra1 = min(w * 16 + 8 + sr, rows - 1);
  const unsigned short* aP0 = act + (size_t)(off + mb * 64 + ra0) * DFF + sc;
  const unsigned short* aP1 = act + (size_t)(off + mb * 64 + ra1) * DFF + sc;
  const int ldsALo = (w * 16) * 64, ldsAHi = (w * 16 + 8) * 64;
  const unsigned short* bP[4];
  int ldsB[4];
#pragma unroll
  for (int i = 0; i < 4; ++i) {
    int rr = w * 32 + i * 8 + sr;
    bP[i] = wdE + (size_t)(c0 + rr) * DFF + sc;
    ldsB[i] = (w * 32 + i * 8) * 64;
  }

  const int fr = l & 15, fq = l >> 4;
  const int wr = (w >> 1) * 32, wc = (w & 1) * 64;
  const int f3 = fr & 7;

  f32x4 acc[2][4];
#pragma unroll
  for (int i = 0; i < 2; ++i)
#pragma unroll
    for (int j = 0; j < 4; ++j) acc[i][j] = (f32x4){0.f, 0.f, 0.f, 0.f};

  auto stage = [&](int b, int kt) {
    gl2lds16(aP0 + kt, &As[b][ldsALo]);
    gl2lds16(aP1 + kt, &As[b][ldsAHi]);
#pragma unroll
    for (int i = 0; i < 4; ++i) gl2lds16(bP[i] + kt, &Bd[b][ldsB[i]]);
  };
  auto compute = [&](int b) {
    short8 af[2][2], bd[4][2];
#pragma unroll
    for (int kk = 0; kk < 2; ++kk) {
      const int ch = ((kk * 4 + fq) ^ f3) * 8;
#pragma unroll
      for (int mi = 0; mi < 2; ++mi)
        af[mi][kk] = *(const short8*)&As[b][(wr + mi * 16 + fr) * 64 + ch];
#pragma unroll
      for (int ni = 0; ni < 4; ++ni)
        bd[ni][kk] = *(const short8*)&Bd[b][(wc + ni * 16 + fr) * 64 + ch];
    }
    __builtin_amdgcn_s_setprio(1);
#pragma unroll
    for (int kk = 0; kk < 2; ++kk)
#pragma unroll
      for (int mi = 0; mi < 2; ++mi)
#pragma unroll
        for (int ni = 0; ni < 4; ++ni)
          acc[mi][ni] = MFMA16(af[mi][kk], bd[ni][kk], acc[mi][ni]);
    __builtin_amdgcn_s_setprio(0);
  };

  const int NK = DFF / 64;     // 22
  stage(0, 0);
  int cur = 0;
  for (int k = 0; k + 1 < NK; ++k) {
    stage(cur ^ 1, (k + 1) * 64);
    asm volatile("s_waitcnt vmcnt(6)" ::: "memory");
    asm volatile("s_barrier" ::: "memory");
    compute(cur);
    asm volatile("s_barrier" ::: "memory");
    cur ^= 1;
  }
  asm volatile("s_waitcnt vmcnt(0)" ::: "memory");
  asm volatile("s_barrier" ::: "memory");
  compute(cur);

#pragma unroll
  for (int mi = 0; mi < 2; ++mi)
#pragma unroll
    for (int ni = 0; ni < 4; ++ni)
#pragma unroll
      for (int j = 0; j < 4; ++j) {
        int r = wr + mi * 16 + fq * 4 + j;
        if (r < rows) {
          int slot = off + mb * 64 + r;
          float v = acc[mi][ni][j] * pair_w[slot];
          atomicAdd(&out[(size_t)pair_token[slot] * HID + (c0 + wc + ni * 16 + fr)], v);
        }
      }
}

extern "C" void kernel_launch(void* const* d_in, const int* in_sizes, int n_in,
                              void* d_out, int out_size, void* d_ws, size_t ws_size,
                              hipStream_t stream) {
  const float* h  = (const float*)d_in[0];
  const float* gw = (const float*)d_in[1];
  const float* wg = (const float*)d_in[2];
  const float* wu = (const float*)d_in[3];
  const float* wd = (const float*)d_in[4];
  float* out = (float*)d_out;

  const size_t SL = (size_t)DFF * HID;
  char* ws = (char*)d_ws;
  int*   cnt        = (int*)(ws + 0);
  int*   offs       = (int*)(ws + 32);
  int*   cursor     = (int*)(ws + 64);
  int*   pair_token = (int*)(ws + 256);
  float* pair_w     = (float*)(ws + 16640);
  int*   topk_idx   = (int*)(ws + 49408);
  float* topk_w     = (float*)(ws + 65792);
  unsigned short* act = (unsigned short*)(ws + 82176);                // 11,534,336
  unsigned short* hbf = (unsigned short*)(ws + 11616512);             //  8,388,608
  unsigned short* wgt = (unsigned short*)(ws + 20005120);             // 46,137,344 (also wd^T)
  unsigned short* wut = (unsigned short*)(ws + 66142464);             // 46,137,344
  const size_t NEED_FULL = 112279808ull;

  hipMemsetAsync(ws, 0, 256, stream);
  hipMemsetAsync(d_out, 0, (size_t)out_size * sizeof(float), stream);

  gate_topk_k<<<N_TOK / 4, 256, 0, stream>>>(h, gw, cnt, topk_idx, topk_w, hbf);
  prefix_k<<<1, 64, 0, stream>>>(cnt, offs, cursor);
  scatter_k<<<N_TOK / 256, 256, 0, stream>>>(topk_idx, topk_w, cursor, pair_token, pair_w);

  if (ws_size >= NEED_FULL) {
    transpose_k<<<dim3(HID / 64, DFF / 64, 16), 256, 0, stream>>>(wg, wgt, wu, wut, HID, DFF, 8);
    gateup9_k<<<176 * 16, 256, 0, stream>>>(hbf, wgt, wut, cnt, offs, pair_token, act,
                                            -1, 176, 22, SL);
    transpose_k<<<dim3(DFF / 64, HID / 64, 8), 256, 0, stream>>>(wd, wgt, wd, wgt, DFF, HID, 8);
    down9_k<<<128 * 16, 256, 0, stream>>>(act, wgt, cnt, offs, pair_token, pair_w, out,
                                          -1, 128, 16, SL);
  } else {
    unsigned short* wgtE = (unsigned short*)(ws + 20005120);
    unsigned short* wutE = (unsigned short*)(ws + 25772288);
    for (int e = 0; e < NEXP; ++e) {
      transpose_k<<<dim3(HID / 64, DFF / 64, 2), 256, 0, stream>>>(wg + e * SL, wgtE, wu + e * SL, wutE, HID, DFF, 1);
      gateup9_k<<<22 * 16, 256, 0, stream>>>(hbf, wgtE, wutE, cnt, offs, pair_token, act,
                                             e, 22, 22, 0);
    }
    for (int e = 0; e < NEXP; ++e) {
      transpose_k<<<dim3(DFF / 64, HID / 64, 1), 256, 0, stream>>>(wd + e * SL, wgtE, wd + e * SL, wgtE, DFF, HID, 1);
      down9_k<<<16 * 16, 256, 0, stream>>>(act, wgtE, cnt, offs, pair_token, pair_w, out,
                                           e, 16, 16, 0);
    }
  }
}

// Round 16
// 305.805 us; speedup vs baseline: 1.3020x; 1.1143x over previous
//
#include <hip/hip_runtime.h>
#include <hip/hip_bf16.h>
#include <stdint.h>

#define N_TOK 2048
#define HID   2048
#define NEXP  8
#define DFF   1408

typedef __attribute__((ext_vector_type(8))) short short8;
typedef __attribute__((ext_vector_type(4))) float f32x4;

__device__ __forceinline__ unsigned short f2bf(float f) {
  union { float ff; uint32_t u; } v; v.ff = f;
  return (unsigned short)((v.u + 0x7FFFu + ((v.u >> 16) & 1u)) >> 16);
}
__device__ __forceinline__ float bf2f(unsigned short u) {
  union { uint32_t i; float f; } v; v.i = (uint32_t)u << 16; return v.f;
}

__device__ __forceinline__ void gl2lds16(const void* g, void* l) {
  __builtin_amdgcn_global_load_lds(
      (const __attribute__((address_space(1))) void*)g,
      (__attribute__((address_space(3))) void*)l, 16, 0, 0);
}

#define MFMA16(a, b, c) __builtin_amdgcn_mfma_f32_16x16x32_bf16((a), (b), (c), 0, 0, 0)

// ---------------- K1: gating + fused h->bf16 conversion ----------------
__global__ __launch_bounds__(256) void gate_topk_k(
    const float* __restrict__ h, const float* __restrict__ gw,
    int* __restrict__ cnt, int* __restrict__ topk_idx, float* __restrict__ topk_w,
    unsigned short* __restrict__ hbf)
{
  int token = blockIdx.x * 4 + (threadIdx.x >> 6);
  int lane  = threadIdx.x & 63;
  const float* hr = h + (size_t)token * HID;
  float acc[NEXP];
#pragma unroll
  for (int e = 0; e < NEXP; ++e) acc[e] = 0.f;
  for (int c = lane * 8; c < HID; c += 512) {
    float4 a = *(const float4*)(hr + c);
    float4 b = *(const float4*)(hr + c + 4);
    unsigned short o[8] = {f2bf(a.x), f2bf(a.y), f2bf(a.z), f2bf(a.w),
                           f2bf(b.x), f2bf(b.y), f2bf(b.z), f2bf(b.w)};
    *(short8*)&hbf[(size_t)token * HID + c] = *(const short8*)o;
#pragma unroll
    for (int e = 0; e < NEXP; ++e) {
      const float* gp = gw + (size_t)e * HID + c;
      float4 ga = *(const float4*)gp;
      float4 gb = *(const float4*)(gp + 4);
      acc[e] = fmaf(a.x, ga.x, fmaf(a.y, ga.y, fmaf(a.z, ga.z, fmaf(a.w, ga.w,
               fmaf(b.x, gb.x, fmaf(b.y, gb.y, fmaf(b.z, gb.z, fmaf(b.w, gb.w, acc[e]))))))));
    }
  }
#pragma unroll
  for (int e = 0; e < NEXP; ++e) {
    float a = acc[e];
#pragma unroll
    for (int s = 32; s > 0; s >>= 1) a += __shfl_xor(a, s, 64);
    acc[e] = a;
  }
  if (lane == 0) {
    float m = acc[0];
#pragma unroll
    for (int e = 1; e < NEXP; ++e) m = fmaxf(m, acc[e]);
    float w[NEXP]; float s = 0.f;
#pragma unroll
    for (int e = 0; e < NEXP; ++e) { w[e] = __expf(acc[e] - m); s += w[e]; }
    float inv = 1.f / s;
    int i0 = 0; float b0 = acc[0];
#pragma unroll
    for (int e = 1; e < NEXP; ++e) if (acc[e] > b0) { b0 = acc[e]; i0 = e; }
    int i1 = -1; float b1 = -3.4e38f;
#pragma unroll
    for (int e = 0; e < NEXP; ++e) if (e != i0 && acc[e] > b1) { b1 = acc[e]; i1 = e; }
    topk_idx[token * 2 + 0] = i0;
    topk_idx[token * 2 + 1] = i1;
    topk_w[token * 2 + 0] = w[i0] * inv;
    topk_w[token * 2 + 1] = w[i1] * inv;
    atomicAdd(&cnt[i0], 1);
    atomicAdd(&cnt[i1], 1);
  }
}

// ---------------- K2: prefix ----------------
__global__ void prefix_k(const int* __restrict__ cnt, int* __restrict__ offs,
                         int* __restrict__ cursor) {
  if (threadIdx.x == 0 && blockIdx.x == 0) {
    int s = 0;
    for (int e = 0; e < NEXP; ++e) { offs[e] = s; cursor[e] = s; s += cnt[e]; }
  }
}

// ---------------- K3: scatter (+ inverse map tok_slot) ----------------
__global__ __launch_bounds__(256) void scatter_k(
    const int* __restrict__ topk_idx, const float* __restrict__ topk_w,
    int* __restrict__ cursor, int* __restrict__ pair_token, float* __restrict__ pair_w,
    int* __restrict__ tok_slot)
{
  int n = blockIdx.x * 256 + threadIdx.x;
  if (n >= N_TOK) return;
#pragma unroll
  for (int k = 0; k < 2; ++k) {
    int e = topk_idx[n * 2 + k];
    int p = atomicAdd(&cursor[e], 1);
    pair_token[p] = n;
    pair_w[p] = topk_w[n * 2 + k];
    tok_slot[n * 2 + k] = p;
  }
}

// ---------------- K5: transpose-convert fp32 [z][R][C] -> bf16 [z][C][R] ----------------
__global__ __launch_bounds__(256) void transpose_k(const float* __restrict__ s1,
                                                   unsigned short* __restrict__ d1,
                                                   const float* __restrict__ s2,
                                                   unsigned short* __restrict__ d2,
                                                   int R, int C, int nz1)
{
  __shared__ unsigned short T[64 * 66];
  const size_t sl = (size_t)R * C;
  int z = blockIdx.z;
  const float* s; unsigned short* d;
  if (z < nz1) { s = s1 + (size_t)z * sl; d = d1 + (size_t)z * sl; }
  else { s = s2 + (size_t)(z - nz1) * sl; d = d2 + (size_t)(z - nz1) * sl; }
  const int rb = blockIdx.x * 64, cb = blockIdx.y * 64;
  const int t = threadIdx.x;
  const int tr = t >> 4, tc = (t & 15) * 4;
  const float* sp = s + (size_t)(rb + tr) * C + cb + tc;
#pragma unroll
  for (int i = 0; i < 4; ++i) {
    float4 v = *(const float4*)(sp + (size_t)i * 16 * C);
    int r = tr + i * 16;
    uint32_t p0 = (uint32_t)f2bf(v.x) | ((uint32_t)f2bf(v.y) << 16);
    uint32_t p1 = (uint32_t)f2bf(v.z) | ((uint32_t)f2bf(v.w) << 16);
    *(uint32_t*)&T[r * 66 + tc]     = p0;
    *(uint32_t*)&T[r * 66 + tc + 2] = p1;
  }
  __syncthreads();
  const int f = t >> 2, ch = (t & 3) * 16;
  unsigned short* dp = d + (size_t)(cb + f) * R + rb + ch;
#pragma unroll
  for (int g = 0; g < 2; ++g) {
    unsigned short buf[8];
#pragma unroll
    for (int j = 0; j < 8; ++j) buf[j] = T[(ch + g * 8 + j) * 66 + f];
    *(short8*)(dp + g * 8) = *(const short8*)buf;
  }
}

// ---------------- K6: grouped GEMM gate+up (64r x 64f dual, 4 waves, 48KB) --------
// R9 champion structure: dbuf + counted vmcnt(6), two barriers, tile queue.
__global__ __launch_bounds__(256) void gateup9_k(
    const unsigned short* __restrict__ hbf,
    const unsigned short* __restrict__ wgt, const unsigned short* __restrict__ wut,
    const int* __restrict__ cnt, const int* __restrict__ offs,
    const int* __restrict__ pair_token, unsigned short* __restrict__ act,
    int e_fixed, int nw, int nbcnt, size_t wstride)
{
  const int x = blockIdx.x;
  const int wti = x % nw, mb = x / nw;
  int e, nb;
  if (e_fixed >= 0) { e = e_fixed; nb = wti; }
  else { e = wti / nbcnt; nb = wti % nbcnt; }
  const int count = cnt[e];
  if (mb * 64 >= count) return;
  const int off = offs[e];
  const int rows = min(64, count - mb * 64);
  const int c0 = nb * 64;

  __shared__ unsigned short As[2][64 * 64];
  __shared__ unsigned short Bg[2][64 * 64];
  __shared__ unsigned short Bu[2][64 * 64];
  __shared__ int tok[64];

  const int t = threadIdx.x;
  if (t < 64) tok[t] = pair_token[off + mb * 64 + min(t, rows - 1)];
  __syncthreads();

  const int w = t >> 6, l = t & 63;
  const int sr = l >> 3;
  const int sc = ((l & 7) ^ sr) * 8;
  const int r0 = w * 16 + sr, r1 = w * 16 + 8 + sr;

  const size_t wb = (e_fixed >= 0) ? 0 : (size_t)e * wstride;
  const unsigned short* wgE = wgt + wb;
  const unsigned short* wuE = wut + wb;
  const unsigned short* aP0 = hbf + (size_t)tok[r0] * HID + sc;
  const unsigned short* aP1 = hbf + (size_t)tok[r1] * HID + sc;
  const unsigned short* gP0 = wgE + (size_t)(c0 + r0) * HID + sc;
  const unsigned short* gP1 = wgE + (size_t)(c0 + r1) * HID + sc;
  const unsigned short* uP0 = wuE + (size_t)(c0 + r0) * HID + sc;
  const unsigned short* uP1 = wuE + (size_t)(c0 + r1) * HID + sc;
  const int ldsLo = (w * 16) * 64, ldsHi = (w * 16 + 8) * 64;

  const int fr = l & 15, fq = l >> 4;
  const int wr = (w >> 1) * 32, wc = (w & 1) * 32;
  const int f3 = fr & 7;

  f32x4 accg[2][2], accu[2][2];
#pragma unroll
  for (int i = 0; i < 2; ++i)
#pragma unroll
    for (int j = 0; j < 2; ++j) {
      accg[i][j] = (f32x4){0.f, 0.f, 0.f, 0.f};
      accu[i][j] = (f32x4){0.f, 0.f, 0.f, 0.f};
    }

  auto stage = [&](int b, int kt) {
    gl2lds16(aP0 + kt, &As[b][ldsLo]); gl2lds16(aP1 + kt, &As[b][ldsHi]);
    gl2lds16(gP0 + kt, &Bg[b][ldsLo]); gl2lds16(gP1 + kt, &Bg[b][ldsHi]);
    gl2lds16(uP0 + kt, &Bu[b][ldsLo]); gl2lds16(uP1 + kt, &Bu[b][ldsHi]);
  };
  auto compute = [&](int b) {
    short8 af[2][2], bg[2][2], bu[2][2];
#pragma unroll
    for (int kk = 0; kk < 2; ++kk) {
      const int ch = ((kk * 4 + fq) ^ f3) * 8;
#pragma unroll
      for (int mi = 0; mi < 2; ++mi)
        af[mi][kk] = *(const short8*)&As[b][(wr + mi * 16 + fr) * 64 + ch];
#pragma unroll
      for (int ni = 0; ni < 2; ++ni) {
        bg[ni][kk] = *(const short8*)&Bg[b][(wc + ni * 16 + fr) * 64 + ch];
        bu[ni][kk] = *(const short8*)&Bu[b][(wc + ni * 16 + fr) * 64 + ch];
      }
    }
    __builtin_amdgcn_s_setprio(1);
#pragma unroll
    for (int kk = 0; kk < 2; ++kk)
#pragma unroll
      for (int mi = 0; mi < 2; ++mi)
#pragma unroll
        for (int ni = 0; ni < 2; ++ni) {
          accg[mi][ni] = MFMA16(af[mi][kk], bg[ni][kk], accg[mi][ni]);
          accu[mi][ni] = MFMA16(af[mi][kk], bu[ni][kk], accu[mi][ni]);
        }
    __builtin_amdgcn_s_setprio(0);
  };

  const int NK = HID / 64;     // 32
  stage(0, 0);
  int cur = 0;
  for (int k = 0; k + 1 < NK; ++k) {
    stage(cur ^ 1, (k + 1) * 64);
    asm volatile("s_waitcnt vmcnt(6)" ::: "memory");
    asm volatile("s_barrier" ::: "memory");
    compute(cur);
    asm volatile("s_barrier" ::: "memory");
    cur ^= 1;
  }
  asm volatile("s_waitcnt vmcnt(0)" ::: "memory");
  asm volatile("s_barrier" ::: "memory");
  compute(cur);

#pragma unroll
  for (int mi = 0; mi < 2; ++mi)
#pragma unroll
    for (int ni = 0; ni < 2; ++ni)
#pragma unroll
      for (int j = 0; j < 4; ++j) {
        int r = wr + mi * 16 + fq * 4 + j;
        if (r < rows) {
          float g = accg[mi][ni][j], u = accu[mi][ni][j];
          float a = (g / (1.f + __expf(-g))) * u;
          act[(size_t)(off + mb * 64 + r) * DFF + (c0 + wc + ni * 16 + fr)] = f2bf(a);
        }
      }
}

// ---------------- K7: grouped GEMM down (64 x 128, 4 waves, 48KB) -> bf16 ypair ---
// R9 champion structure; bf16 store halves ypair traffic (validated R11/R12).
__global__ __launch_bounds__(256) void down9_k(
    const unsigned short* __restrict__ act, const unsigned short* __restrict__ wdt,
    const int* __restrict__ cnt, const int* __restrict__ offs,
    unsigned short* __restrict__ ypair, int e_fixed, int nw, int nbcnt, size_t wstride)
{
  const int x = blockIdx.x;
  const int wti = x % nw, mb = x / nw;
  int e, nb;
  if (e_fixed >= 0) { e = e_fixed; nb = wti; }
  else { e = wti / nbcnt; nb = wti % nbcnt; }
  const int count = cnt[e];
  if (mb * 64 >= count) return;
  const int off = offs[e];
  const int rows = min(64, count - mb * 64);
  const int c0 = nb * 128;

  __shared__ unsigned short As[2][64 * 64];
  __shared__ unsigned short Bd[2][128 * 64];

  const int t = threadIdx.x;
  const int w = t >> 6, l = t & 63;
  const int sr = l >> 3;
  const int sc = ((l & 7) ^ sr) * 8;
  const size_t wb = (e_fixed >= 0) ? 0 : (size_t)e * wstride;
  const unsigned short* wdE = wdt + wb;

  const int ra0 = min(w * 16 + sr, rows - 1), ra1 = min(w * 16 + 8 + sr, rows - 1);
  const unsigned short* aP0 = act + (size_t)(off + mb * 64 + ra0) * DFF + sc;
  const unsigned short* aP1 = act + (size_t)(off + mb * 64 + ra1) * DFF + sc;
  const int ldsALo = (w * 16) * 64, ldsAHi = (w * 16 + 8) * 64;
  const unsigned short* bP[4];
  int ldsB[4];
#pragma unroll
  for (int i = 0; i < 4; ++i) {
    int rr = w * 32 + i * 8 + sr;
    bP[i] = wdE + (size_t)(c0 + rr) * DFF + sc;
    ldsB[i] = (w * 32 + i * 8) * 64;
  }

  const int fr = l & 15, fq = l >> 4;
  const int wr = (w >> 1) * 32, wc = (w & 1) * 64;
  const int f3 = fr & 7;

  f32x4 acc[2][4];
#pragma unroll
  for (int i = 0; i < 2; ++i)
#pragma unroll
    for (int j = 0; j < 4; ++j) acc[i][j] = (f32x4){0.f, 0.f, 0.f, 0.f};

  auto stage = [&](int b, int kt) {
    gl2lds16(aP0 + kt, &As[b][ldsALo]);
    gl2lds16(aP1 + kt, &As[b][ldsAHi]);
#pragma unroll
    for (int i = 0; i < 4; ++i) gl2lds16(bP[i] + kt, &Bd[b][ldsB[i]]);
  };
  auto compute = [&](int b) {
    short8 af[2][2], bd[4][2];
#pragma unroll
    for (int kk = 0; kk < 2; ++kk) {
      const int ch = ((kk * 4 + fq) ^ f3) * 8;
#pragma unroll
      for (int mi = 0; mi < 2; ++mi)
        af[mi][kk] = *(const short8*)&As[b][(wr + mi * 16 + fr) * 64 + ch];
#pragma unroll
      for (int ni = 0; ni < 4; ++ni)
        bd[ni][kk] = *(const short8*)&Bd[b][(wc + ni * 16 + fr) * 64 + ch];
    }
    __builtin_amdgcn_s_setprio(1);
#pragma unroll
    for (int kk = 0; kk < 2; ++kk)
#pragma unroll
      for (int mi = 0; mi < 2; ++mi)
#pragma unroll
        for (int ni = 0; ni < 4; ++ni)
          acc[mi][ni] = MFMA16(af[mi][kk], bd[ni][kk], acc[mi][ni]);
    __builtin_amdgcn_s_setprio(0);
  };

  const int NK = DFF / 64;     // 22
  stage(0, 0);
  int cur = 0;
  for (int k = 0; k + 1 < NK; ++k) {
    stage(cur ^ 1, (k + 1) * 64);
    asm volatile("s_waitcnt vmcnt(6)" ::: "memory");
    asm volatile("s_barrier" ::: "memory");
    compute(cur);
    asm volatile("s_barrier" ::: "memory");
    cur ^= 1;
  }
  asm volatile("s_waitcnt vmcnt(0)" ::: "memory");
  asm volatile("s_barrier" ::: "memory");
  compute(cur);

#pragma unroll
  for (int mi = 0; mi < 2; ++mi)
#pragma unroll
    for (int ni = 0; ni < 4; ++ni)
#pragma unroll
      for (int j = 0; j < 4; ++j) {
        int r = wr + mi * 16 + fq * 4 + j;
        if (r < rows)
          ypair[(size_t)(off + mb * 64 + r) * HID + (c0 + wc + ni * 16 + fr)] = f2bf(acc[mi][ni][j]);
      }
}

// ---------------- K8: weighted combine (bf16 ypair) ----------------
__global__ __launch_bounds__(256) void combine_k(
    const unsigned short* __restrict__ ypair, const int* __restrict__ tok_slot,
    const float* __restrict__ topk_w, float* __restrict__ out)
{
  int i = blockIdx.x * 256 + threadIdx.x;       // over N_TOK * HID/8
  int n = i >> 8;
  int dv = (i & 255) * 8;
  int s0 = tok_slot[n * 2], s1 = tok_slot[n * 2 + 1];
  float w0 = topk_w[n * 2], w1 = topk_w[n * 2 + 1];
  short8 a = *(const short8*)&ypair[(size_t)s0 * HID + dv];
  short8 b = *(const short8*)&ypair[(size_t)s1 * HID + dv];
  float o[8];
#pragma unroll
  for (int j = 0; j < 8; ++j)
    o[j] = w0 * bf2f((unsigned short)a[j]) + w1 * bf2f((unsigned short)b[j]);
  *(float4*)&out[(size_t)n * HID + dv]     = *(const float4*)&o[0];
  *(float4*)&out[(size_t)n * HID + dv + 4] = *(const float4*)&o[4];
}

extern "C" void kernel_launch(void* const* d_in, const int* in_sizes, int n_in,
                              void* d_out, int out_size, void* d_ws, size_t ws_size,
                              hipStream_t stream) {
  const float* h  = (const float*)d_in[0];
  const float* gw = (const float*)d_in[1];
  const float* wg = (const float*)d_in[2];
  const float* wu = (const float*)d_in[3];
  const float* wd = (const float*)d_in[4];
  float* out = (float*)d_out;

  const size_t SL = (size_t)DFF * HID;
  char* ws = (char*)d_ws;
  int*   cnt        = (int*)(ws + 0);
  int*   offs       = (int*)(ws + 32);
  int*   cursor     = (int*)(ws + 64);
  int*   pair_token = (int*)(ws + 256);
  float* pair_w     = (float*)(ws + 16640);
  int*   tok_slot   = (int*)(ws + 33024);
  int*   topk_idx   = (int*)(ws + 49408);
  float* topk_w     = (float*)(ws + 65792);
  unsigned short* act = (unsigned short*)(ws + 82176);                // 11,534,336
  unsigned short* hbf = (unsigned short*)(ws + 11616512);             //  8,388,608
  unsigned short* wgt = (unsigned short*)(ws + 20005120);             // 46,137,344 (also wd^T)
  unsigned short* wut = (unsigned short*)(ws + 66142464);             // 46,137,344
  unsigned short* ypair_full = (unsigned short*)(ws + 66142464);      // aliases wut (down phase)
  const size_t NEED_FULL = 112279808ull;

  hipMemsetAsync(ws, 0, 256, stream);

  gate_topk_k<<<N_TOK / 4, 256, 0, stream>>>(h, gw, cnt, topk_idx, topk_w, hbf);
  prefix_k<<<1, 64, 0, stream>>>(cnt, offs, cursor);
  scatter_k<<<N_TOK / 256, 256, 0, stream>>>(topk_idx, topk_w, cursor, pair_token, pair_w, tok_slot);

  if (ws_size >= NEED_FULL) {
    transpose_k<<<dim3(HID / 64, DFF / 64, 16), 256, 0, stream>>>(wg, wgt, wu, wut, HID, DFF, 8);
    gateup9_k<<<176 * 16, 256, 0, stream>>>(hbf, wgt, wut, cnt, offs, pair_token, act,
                                            -1, 176, 22, SL);
    transpose_k<<<dim3(DFF / 64, HID / 64, 8), 256, 0, stream>>>(wd, wgt, wd, wgt, DFF, HID, 8);
    down9_k<<<128 * 16, 256, 0, stream>>>(act, wgt, cnt, offs, ypair_full,
                                          -1, 128, 16, SL);
    combine_k<<<(N_TOK * HID / 8) / 256, 256, 0, stream>>>(ypair_full, tok_slot, topk_w, out);
  } else {
    unsigned short* wgtE = (unsigned short*)(ws + 20005120);
    unsigned short* wutE = (unsigned short*)(ws + 25772288);
    unsigned short* ypair = (unsigned short*)(ws + 31539456);
    for (int e = 0; e < NEXP; ++e) {
      transpose_k<<<dim3(HID / 64, DFF / 64, 2), 256, 0, stream>>>(wg + e * SL, wgtE, wu + e * SL, wutE, HID, DFF, 1);
      gateup9_k<<<22 * 16, 256, 0, stream>>>(hbf, wgtE, wutE, cnt, offs, pair_token, act,
                                             e, 22, 22, 0);
    }
    for (int e = 0; e < NEXP; ++e) {
      transpose_k<<<dim3(DFF / 64, HID / 64, 1), 256, 0, stream>>>(wd + e * SL, wgtE, wd + e * SL, wgtE, DFF, HID, 1);
      down9_k<<<16 * 16, 256, 0, stream>>>(act, wgtE, cnt, offs, ypair, e, 16, 16, 0);
    }
    combine_k<<<(N_TOK * HID / 8) / 256, 256, 0, stream>>>(ypair, tok_slot, topk_w, out);
  }
}